// Round 3
// baseline (444.970 us; speedup 1.0000x reference)
//
#include <hip/hip_runtime.h>

typedef short bf16x8 __attribute__((ext_vector_type(8)));
typedef float f32x16 __attribute__((ext_vector_type(16)));

#define NBGROUPS 128
#define TILES_PER_BLOCK 64   // (262144/32)/NBGROUPS
#define SCALE 4.7746482927568601f   // 30 / (2*pi): weights pre-scaled -> args in revolutions

union Frag { bf16x8 v; unsigned u[4]; uint4 q; };

__device__ __forceinline__ unsigned pk_bf16(float lo, float hi) {
    unsigned r;
    asm("v_cvt_pk_bf16_f32 %0, %1, %2" : "=v"(r) : "v"(lo), "v"(hi));
    return r;
}
__device__ __forceinline__ float lo_f(unsigned w) { return __uint_as_float(w << 16); }
__device__ __forceinline__ float hi_f(unsigned w) { return __uint_as_float(w & 0xffff0000u); }

// sin(2*pi*z) via exact range reduction + odd deg-13 Taylor on v in [-0.5,0.5].
// v = (z - floor(z)) - 0.5 (exact);  sin(2*pi*z) = -sin(2*pi*v); minus folded into coeffs.
// Max poly error ~2.2e-5 (first dropped Taylor term at |v|=0.5).
__device__ __forceinline__ float sin_rev(float z) {
    float v  = (z - floorf(z)) - 0.5f;
    float v2 = v * v;
    float p  = -3.81995f;
    p = fmaf(p, v2,  15.09466f);
    p = fmaf(p, v2, -42.0587370f);
    p = fmaf(p, v2,  76.7058597f);
    p = fmaf(p, v2, -81.6052493f);
    p = fmaf(p, v2,  41.3417022f);
    p = fmaf(p, v2, -6.28318531f);
    return p * v;
}

// Bias table layout: [((Lb*2+tg)*4+q)*2 + hi], Lb=0..2 mid layers, Lb=3 first layer. Pre-scaled by SCALE.
__device__ __forceinline__ void init_acc(f32x16* acc, const float4* ldsBias, int Lb, int hi) {
#pragma unroll
    for (int tg = 0; tg < 2; ++tg) {
#pragma unroll
        for (int q = 0; q < 4; ++q) {
            float4 b4 = ldsBias[((Lb*2+tg)*4+q)*2 + hi];
            acc[tg][q*4+0] = b4.x; acc[tg][q*4+1] = b4.y;
            acc[tg][q*4+2] = b4.z; acc[tg][q*4+3] = b4.w;
        }
    }
}

// acc (f32, D layout row=(r&3)+8*(r>>2)+4*hi) -> sin -> hi/lo-split bf16 B-frags.
// B k-slot convention (self-consistent with A packing): frag c=(tg,s), word wi, half p:
//   h = 32*tg + 16*s + 2*(wi&1) + p + 8*(wi>>1) + 4*hi
__device__ __forceinline__ void transition(const f32x16* acc, Frag* Bhi, Frag* Blo) {
#pragma unroll
    for (int tg = 0; tg < 2; ++tg) {
        float sv[16];
#pragma unroll
        for (int r = 0; r < 16; ++r) sv[r] = sin_rev(acc[tg][r]);
#pragma unroll
        for (int s = 0; s < 2; ++s)
#pragma unroll
            for (int wi = 0; wi < 4; ++wi) {
                float a = sv[s*8 + 2*wi], b = sv[s*8 + 2*wi + 1];
                unsigned ph = pk_bf16(a, b);
                Bhi[tg*2+s].u[wi] = ph;
                Blo[tg*2+s].u[wi] = pk_bf16(a - lo_f(ph), b - hi_f(ph));
            }
    }
}

__global__ __launch_bounds__(256, 3)
void siren_kernel(const float* __restrict__ x, const float* __restrict__ W0m,
                  const float* __restrict__ b0, const float* __restrict__ Wm,
                  const float* __restrict__ bm, const float* __restrict__ Wl,
                  const float* __restrict__ bl, float* __restrict__ out)
{
    __shared__ uint4  ldsAhi[3*2*4*64];   // mid-layer A hi-frags, 24KB
    __shared__ uint4  ldsAlo[3*2*4*64];   // mid-layer A lo-frags, 24KB
    __shared__ float4 ldsBias[4*2*4*2];   // 1KB, pre-scaled biases

    const int tid  = threadIdx.x;
    const int o    = blockIdx.x / NBGROUPS;   // subnet
    const int pg   = blockIdx.x % NBGROUPS;   // point group
    const int lane = tid & 63;
    const int wv   = tid >> 6;
    const int col  = lane & 31;
    const int hi   = lane >> 5;

    // ---- stage mid-layer weight fragments, hi/lo compensated, pre-scaled by SCALE ----
    for (int idx = tid; idx < 3*2*4*64; idx += 256) {
        int l2  = idx & 63;
        int fi  = idx >> 6;
        int c   = fi & 3;
        int tg  = (fi >> 2) & 1;
        int L   = fi >> 3;
        int hi2 = l2 >> 5;
        int g   = tg*32 + (l2 & 31);
        int th  = c >> 1, s = c & 1;
        const float2* Wrow2 = (const float2*)(Wm + (((size_t)(L*16 + o)*64 + g)*64));
        uint4 whi, wlo;
        unsigned* uh = (unsigned*)&whi;
        unsigned* ul = (unsigned*)&wlo;
#pragma unroll
        for (int wi = 0; wi < 4; ++wi) {
            int h = th*32 + s*16 + 8*(wi>>1) + 2*(wi&1) + 4*hi2;   // always even
            float2 wp = Wrow2[h >> 1];
            float a = SCALE*wp.x, b = SCALE*wp.y;
            unsigned ph = pk_bf16(a, b);
            uh[wi] = ph;
            ul[wi] = pk_bf16(a - lo_f(ph), b - hi_f(ph));
        }
        ldsAhi[idx] = whi;
        ldsAlo[idx] = wlo;
    }
    // ---- stage biases (pre-scaled) in accumulator layout ----
    if (tid < 64) {
        int hi2 = tid & 1;
        int q   = (tid >> 1) & 3;
        int tg  = (tid >> 3) & 1;
        int Lb  = tid >> 4;          // 0..2 mid, 3 = first layer
        int h0  = tg*32 + 8*q + 4*hi2;
        const float* bsrc = (Lb < 3) ? (bm + (Lb*16 + o)*64) : (b0 + o*64);
        ldsBias[tid] = make_float4(SCALE*bsrc[h0], SCALE*bsrc[h0+1],
                                   SCALE*bsrc[h0+2], SCALE*bsrc[h0+3]);
    }

    // ---- first-layer A frags, fully compensated in the 4 k-slot words ----
    Frag L1A[2];
#pragma unroll
    for (int tg = 0; tg < 2; ++tg) {
        int g = tg*32 + col;
        float2 wp = ((const float2*)W0m)[o*64 + g];
        float s0 = SCALE*wp.x, s1 = SCALE*wp.y;
        unsigned u0 = pk_bf16(s0, s0), u1 = pk_bf16(s1, s1);
        float l0 = s0 - lo_f(u0), l1 = s1 - lo_f(u1);
        L1A[tg].u[0] = hi ? 0u : u0;
        L1A[tg].u[1] = hi ? 0u : u1;
        L1A[tg].u[2] = hi ? 0u : pk_bf16(l0, l0);
        L1A[tg].u[3] = hi ? 0u : pk_bf16(l1, l1);
    }
    // ---- last-layer weights, f32, per-lane in this lane's acc slot order ----
    float Wlf[32];
#pragma unroll
    for (int tg = 0; tg < 2; ++tg)
#pragma unroll
        for (int r = 0; r < 16; ++r) {
            int s = r >> 3, j = r & 7;
            int h = tg*32 + 16*s + (j & 3) + 8*(j >> 2) + 4*hi;
            Wlf[tg*16 + r] = Wl[o*64 + h];
        }
    const float blv = bl[o] + 0.5f;

    __syncthreads();

    for (int it = 0; it < TILES_PER_BLOCK/4; ++it) {
        const int tile = pg*TILES_PER_BLOCK + it*4 + wv;
        const int pp   = tile*32 + col;

        // first-layer B: x split hi/lo (exact), duplicated for the W-lo slots
        float2 xv = ((const float2*)x)[pp];
        unsigned ux = pk_bf16(xv.x, xv.y);
        float x0h = lo_f(ux), x1h = hi_f(ux);
        unsigned w0 = pk_bf16(x0h, xv.x - x0h);
        unsigned w1 = pk_bf16(x1h, xv.y - x1h);
        Frag B1;
        B1.u[0] = hi ? 0u : w0;
        B1.u[1] = hi ? 0u : w1;
        B1.u[2] = hi ? 0u : w0;
        B1.u[3] = hi ? 0u : w1;

        f32x16 acc[2];
        init_acc(acc, ldsBias, 3, hi);
        acc[0] = __builtin_amdgcn_mfma_f32_32x32x16_bf16(L1A[0].v, B1.v, acc[0], 0, 0, 0);
        acc[1] = __builtin_amdgcn_mfma_f32_32x32x16_bf16(L1A[1].v, B1.v, acc[1], 0, 0, 0);

        Frag Bhi[4], Blo[4];
        transition(acc, Bhi, Blo);

#pragma unroll
        for (int L = 0; L < 3; ++L) {
            init_acc(acc, ldsBias, L, hi);
#pragma unroll
            for (int c = 0; c < 4; ++c) {
                Frag Ah0, Ah1, Al0, Al1;
                Ah0.q = ldsAhi[((L*2+0)*4+c)*64 + lane];
                Ah1.q = ldsAhi[((L*2+1)*4+c)*64 + lane];
                Al0.q = ldsAlo[((L*2+0)*4+c)*64 + lane];
                Al1.q = ldsAlo[((L*2+1)*4+c)*64 + lane];
                // 3-term compensated product; two independent acc chains interleaved
                acc[0] = __builtin_amdgcn_mfma_f32_32x32x16_bf16(Ah0.v, Bhi[c].v, acc[0], 0, 0, 0);
                acc[1] = __builtin_amdgcn_mfma_f32_32x32x16_bf16(Ah1.v, Bhi[c].v, acc[1], 0, 0, 0);
                acc[0] = __builtin_amdgcn_mfma_f32_32x32x16_bf16(Ah0.v, Blo[c].v, acc[0], 0, 0, 0);
                acc[1] = __builtin_amdgcn_mfma_f32_32x32x16_bf16(Ah1.v, Blo[c].v, acc[1], 0, 0, 0);
                acc[0] = __builtin_amdgcn_mfma_f32_32x32x16_bf16(Al0.v, Bhi[c].v, acc[0], 0, 0, 0);
                acc[1] = __builtin_amdgcn_mfma_f32_32x32x16_bf16(Al1.v, Bhi[c].v, acc[1], 0, 0, 0);
            }
            if (L < 2) transition(acc, Bhi, Blo);
        }

        // last layer: f32 sin + f32 dot (no bf16 anywhere), then half-swap reduce
        float sum = 0.f;
#pragma unroll
        for (int tg = 0; tg < 2; ++tg)
#pragma unroll
            for (int r = 0; r < 16; ++r)
                sum = fmaf(sin_rev(acc[tg][r]), Wlf[tg*16 + r], sum);
        sum += __shfl_xor(sum, 32);
        if (lane < 32) out[(size_t)pp*16 + o] = sum + blv;
    }
}

extern "C" void kernel_launch(void* const* d_in, const int* in_sizes, int n_in,
                              void* d_out, int out_size, void* d_ws, size_t ws_size,
                              hipStream_t stream) {
    (void)in_sizes; (void)n_in; (void)out_size; (void)d_ws; (void)ws_size;
    siren_kernel<<<dim3(16*NBGROUPS), dim3(256), 0, stream>>>(
        (const float*)d_in[0], (const float*)d_in[1], (const float*)d_in[2],
        (const float*)d_in[3], (const float*)d_in[4], (const float*)d_in[5],
        (const float*)d_in[6], (float*)d_out);
}

// Round 4
// 397.463 us; speedup vs baseline: 1.1195x; 1.1195x over previous
//
#include <hip/hip_runtime.h>

typedef short bf16x8 __attribute__((ext_vector_type(8)));
typedef float f32x16 __attribute__((ext_vector_type(16)));

#define NBGROUPS 96          // grid = 16 x 96 = 1536 blocks; divides 768- and 512-resident evenly
#define NTILES   8192        // 262144/32 point-tiles per subnet
#define SCALE 4.7746482927568601f   // 30/(2*pi): weights pre-scaled -> args in revolutions

union Frag  { bf16x8 v; unsigned u[4]; uint4 q; };
union AccLd { float4 f4[4]; f32x16 v; };

__device__ __forceinline__ unsigned pk_bf16(float lo, float hi) {
    unsigned r;
    asm("v_cvt_pk_bf16_f32 %0, %1, %2" : "=v"(r) : "v"(lo), "v"(hi));
    return r;
}
__device__ __forceinline__ float lo_f(unsigned w) { return __uint_as_float(w << 16); }
__device__ __forceinline__ float hi_f(unsigned w) { return __uint_as_float(w & 0xffff0000u); }

// sin(2*pi*z): v = z - rndne(z) in [-0.5,0.5] (exact), then deg-9 Chebyshev-truncated
// poly for sin(2*pi*v) (coeffs 2^{k}*2*J-Bessel expansion; max err ~6e-6).
__device__ __forceinline__ float sin_rev(float z) {
    float v  = z - rintf(z);
    float v2 = v * v;
    float p  = 32.765379f;
    p = fmaf(p, v2, -74.468884f);
    p = fmaf(p, v2,  81.365064f);
    p = fmaf(p, v2, -41.331084f);
    p = fmaf(p, v2,   6.2830526f);
    return p * v;
}

// Bias table: [ ((Lb*2+tg)*2 + hi)*4 + q ] float4, contiguous 64B per (Lb,tg,hi).
__device__ __forceinline__ void init_acc(f32x16* acc, const float4* ldsBias, int Lb, int hi) {
#pragma unroll
    for (int tg = 0; tg < 2; ++tg) {
        AccLd a;
        const float4* base = &ldsBias[((Lb*2+tg)*2 + hi)*4];
#pragma unroll
        for (int q = 0; q < 4; ++q) a.f4[q] = base[q];
        acc[tg] = a.v;
    }
}

// acc (D layout row=(r&3)+8*(r>>2)+4*hi) -> sin -> hi/lo bf16 B-frags.
// B k-slot map (self-consistent with A staging): frag c=(tg,s), word wi, half p:
//   h = 32*tg + 16*s + 2*(wi&1) + p + 8*(wi>>1) + 4*hi
__device__ __forceinline__ void transitionHL(const f32x16* acc, Frag* Bhi, Frag* Blo) {
#pragma unroll
    for (int tg = 0; tg < 2; ++tg) {
        float sv[16];
#pragma unroll
        for (int r = 0; r < 16; ++r) sv[r] = sin_rev(acc[tg][r]);
#pragma unroll
        for (int s = 0; s < 2; ++s)
#pragma unroll
            for (int wi = 0; wi < 4; ++wi) {
                float a = sv[s*8 + 2*wi], b = sv[s*8 + 2*wi + 1];
                unsigned ph = pk_bf16(a, b);
                Bhi[tg*2+s].u[wi] = ph;
                Blo[tg*2+s].u[wi] = pk_bf16(a - lo_f(ph), b - hi_f(ph));
            }
    }
}
// hi-only variant for the final transition (error gain < 1 through last dot)
__device__ __forceinline__ void transitionH(const f32x16* acc, Frag* Bhi) {
#pragma unroll
    for (int tg = 0; tg < 2; ++tg) {
        float sv[16];
#pragma unroll
        for (int r = 0; r < 16; ++r) sv[r] = sin_rev(acc[tg][r]);
#pragma unroll
        for (int s = 0; s < 2; ++s)
#pragma unroll
            for (int wi = 0; wi < 4; ++wi)
                Bhi[tg*2+s].u[wi] = pk_bf16(sv[s*8 + 2*wi], sv[s*8 + 2*wi + 1]);
    }
}

__global__ __launch_bounds__(256, 3)
void siren_kernel(const float* __restrict__ x, const float* __restrict__ W0m,
                  const float* __restrict__ b0, const float* __restrict__ Wm,
                  const float* __restrict__ bm, const float* __restrict__ Wl,
                  const float* __restrict__ bl, float* __restrict__ out)
{
    __shared__ uint4  ldsAhi[3*2*4*64];   // 24KB
    __shared__ uint4  ldsAlo[3*2*4*64];   // 24KB
    __shared__ float4 ldsBias[4*2*2*4];   // 1KB

    const int tid  = threadIdx.x;
    const int pg   = blockIdx.x;          // point group (0..95)
    const int o    = blockIdx.y;          // subnet (0..15)
    const int lane = tid & 63;
    const int wv   = tid >> 6;
    const int col  = lane & 31;
    const int hi   = lane >> 5;

    // ---- stage mid-layer weight fragments, hi/lo compensated, pre-scaled ----
    for (int idx = tid; idx < 3*2*4*64; idx += 256) {
        int l2  = idx & 63;
        int fi  = idx >> 6;
        int c   = fi & 3;
        int tg  = (fi >> 2) & 1;
        int L   = fi >> 3;
        int hi2 = l2 >> 5;
        int g   = tg*32 + (l2 & 31);
        int th  = c >> 1, s = c & 1;
        const float2* Wrow2 = (const float2*)(Wm + (((size_t)(L*16 + o)*64 + g)*64));
        uint4 whi, wlo;
        unsigned* uh = (unsigned*)&whi;
        unsigned* ul = (unsigned*)&wlo;
#pragma unroll
        for (int wi = 0; wi < 4; ++wi) {
            int h = th*32 + s*16 + 8*(wi>>1) + 2*(wi&1) + 4*hi2;   // even
            float2 wp = Wrow2[h >> 1];
            float a = SCALE*wp.x, b = SCALE*wp.y;
            unsigned ph = pk_bf16(a, b);
            uh[wi] = ph;
            ul[wi] = pk_bf16(a - lo_f(ph), b - hi_f(ph));
        }
        ldsAhi[idx] = whi;
        ldsAlo[idx] = wlo;
    }
    // ---- stage biases (pre-scaled), contiguous per (Lb,tg,hi) ----
    if (tid < 64) {
        int q   = tid & 3;
        int hi2 = (tid >> 2) & 1;
        int tg  = (tid >> 3) & 1;
        int Lb  = tid >> 4;          // 0..2 mid, 3 = first layer
        int h0  = tg*32 + 8*q + 4*hi2;
        const float* bsrc = (Lb < 3) ? (bm + (Lb*16 + o)*64) : (b0 + o*64);
        ldsBias[tid] = make_float4(SCALE*bsrc[h0], SCALE*bsrc[h0+1],
                                   SCALE*bsrc[h0+2], SCALE*bsrc[h0+3]);
    }

    // ---- first-layer A frags, fully compensated ----
    Frag L1A[2];
#pragma unroll
    for (int tg = 0; tg < 2; ++tg) {
        int g = tg*32 + col;
        float2 wp = ((const float2*)W0m)[o*64 + g];
        float s0 = SCALE*wp.x, s1 = SCALE*wp.y;
        unsigned u0 = pk_bf16(s0, s0), u1 = pk_bf16(s1, s1);
        float l0 = s0 - lo_f(u0), l1 = s1 - lo_f(u1);
        L1A[tg].u[0] = hi ? 0u : u0;
        L1A[tg].u[1] = hi ? 0u : u1;
        L1A[tg].u[2] = hi ? 0u : pk_bf16(l0, l0);
        L1A[tg].u[3] = hi ? 0u : pk_bf16(l1, l1);
    }
    // ---- last-layer A frags: row 0 = Wl (unscaled), only lanes with col==0 carry data ----
    Frag WlA[4];
#pragma unroll
    for (int c = 0; c < 4; ++c) { WlA[c].u[0]=0u; WlA[c].u[1]=0u; WlA[c].u[2]=0u; WlA[c].u[3]=0u; }
    if (col == 0) {
        const float2* Wl2 = (const float2*)(Wl + o*64);
#pragma unroll
        for (int c = 0; c < 4; ++c) {
            int tg = c >> 1, s = c & 1;
#pragma unroll
            for (int wi = 0; wi < 4; ++wi) {
                int h = tg*32 + s*16 + 8*(wi>>1) + 2*(wi&1) + 4*hi;
                float2 wp = Wl2[h >> 1];
                WlA[c].u[wi] = pk_bf16(wp.x, wp.y);
            }
        }
    }
    const float blv = bl[o] + 0.5f;

    __syncthreads();

    const int tend = ((pg + 1) * NTILES) / NBGROUPS;
    for (int t = (pg * NTILES) / NBGROUPS + wv; t < tend; t += 4) {
        const int pp = t*32 + col;

        // first-layer B: x split hi/lo (exact), duplicated for the W-lo slots
        float2 xv = ((const float2*)x)[pp];
        unsigned ux = pk_bf16(xv.x, xv.y);
        float x0h = lo_f(ux), x1h = hi_f(ux);
        unsigned w0 = pk_bf16(x0h, xv.x - x0h);
        unsigned w1 = pk_bf16(x1h, xv.y - x1h);
        Frag B1;
        B1.u[0] = hi ? 0u : w0;
        B1.u[1] = hi ? 0u : w1;
        B1.u[2] = hi ? 0u : w0;
        B1.u[3] = hi ? 0u : w1;

        f32x16 acc[2];
        init_acc(acc, ldsBias, 3, hi);
        acc[0] = __builtin_amdgcn_mfma_f32_32x32x16_bf16(L1A[0].v, B1.v, acc[0], 0, 0, 0);
        acc[1] = __builtin_amdgcn_mfma_f32_32x32x16_bf16(L1A[1].v, B1.v, acc[1], 0, 0, 0);

        Frag Bhi[4], Blo[4];
        transitionHL(acc, Bhi, Blo);

#pragma unroll
        for (int L = 0; L < 3; ++L) {
            init_acc(acc, ldsBias, L, hi);
#pragma unroll
            for (int c = 0; c < 4; ++c) {
                Frag Ah0, Ah1, Al0, Al1;
                Ah0.q = ldsAhi[((L*2+0)*4+c)*64 + lane];
                Ah1.q = ldsAhi[((L*2+1)*4+c)*64 + lane];
                Al0.q = ldsAlo[((L*2+0)*4+c)*64 + lane];
                Al1.q = ldsAlo[((L*2+1)*4+c)*64 + lane];
                acc[0] = __builtin_amdgcn_mfma_f32_32x32x16_bf16(Ah0.v, Bhi[c].v, acc[0], 0, 0, 0);
                acc[1] = __builtin_amdgcn_mfma_f32_32x32x16_bf16(Ah1.v, Bhi[c].v, acc[1], 0, 0, 0);
                acc[0] = __builtin_amdgcn_mfma_f32_32x32x16_bf16(Ah0.v, Blo[c].v, acc[0], 0, 0, 0);
                acc[1] = __builtin_amdgcn_mfma_f32_32x32x16_bf16(Ah1.v, Blo[c].v, acc[1], 0, 0, 0);
                acc[0] = __builtin_amdgcn_mfma_f32_32x32x16_bf16(Al0.v, Bhi[c].v, acc[0], 0, 0, 0);
                acc[1] = __builtin_amdgcn_mfma_f32_32x32x16_bf16(Al1.v, Bhi[c].v, acc[1], 0, 0, 0);
            }
            if (L < 2) transitionHL(acc, Bhi, Blo);
        }

        // final transition: hi-only pack, then last layer as MFMA (row 0 = Wl)
        transitionH(acc, Bhi);
        f32x16 facc;
#pragma unroll
        for (int i = 0; i < 16; ++i) facc[i] = 0.f;
        facc[0] = blv;
#pragma unroll
        for (int c = 0; c < 4; ++c)
            facc = __builtin_amdgcn_mfma_f32_32x32x16_bf16(WlA[c].v, Bhi[c].v, facc, 0, 0, 0);
        if (lane < 32) out[(size_t)pp*16 + o] = facc[0];
    }
}

extern "C" void kernel_launch(void* const* d_in, const int* in_sizes, int n_in,
                              void* d_out, int out_size, void* d_ws, size_t ws_size,
                              hipStream_t stream) {
    (void)in_sizes; (void)n_in; (void)out_size; (void)d_ws; (void)ws_size;
    siren_kernel<<<dim3(NBGROUPS, 16), dim3(256), 0, stream>>>(
        (const float*)d_in[0], (const float*)d_in[1], (const float*)d_in[2],
        (const float*)d_in[3], (const float*)d_in[4], (const float*)d_in[5],
        (const float*)d_in[6], (float*)d_out);
}

// Round 5
// 394.562 us; speedup vs baseline: 1.1278x; 1.0074x over previous
//
#include <hip/hip_runtime.h>

typedef short bf16x8 __attribute__((ext_vector_type(8)));
typedef float f32x16 __attribute__((ext_vector_type(16)));

#define NBGROUPS 96          // grid = 96 x 16 = 1536 blocks
#define NTILES   8192        // 262144/32 point-tiles per subnet
#define SCALE 4.7746482927568601f   // 30/(2*pi): weights pre-scaled -> args in revolutions

union Frag  { bf16x8 v; unsigned u[4]; uint4 q; };
union AccLd { float4 f4[4]; f32x16 v; };

__device__ __forceinline__ unsigned pk_bf16(float lo, float hi) {
    unsigned r;
    asm("v_cvt_pk_bf16_f32 %0, %1, %2" : "=v"(r) : "v"(lo), "v"(hi));
    return r;
}
__device__ __forceinline__ float lo_f(unsigned w) { return __uint_as_float(w << 16); }
__device__ __forceinline__ float hi_f(unsigned w) { return __uint_as_float(w & 0xffff0000u); }

// sin(2*pi*z): v = z - rndne(z) in [-0.5,0.5] (exact), deg-9 poly, max err ~6e-6.
__device__ __forceinline__ float sin_rev(float z) {
    float v  = z - rintf(z);
    float v2 = v * v;
    float p  = 32.765379f;
    p = fmaf(p, v2, -74.468884f);
    p = fmaf(p, v2,  81.365064f);
    p = fmaf(p, v2, -41.331084f);
    p = fmaf(p, v2,   6.2830526f);
    return p * v;
}

// Bias table: [ ((Lb*2+tg)*2 + hi)*4 + q ] float4, contiguous 64B per (Lb,tg,hi).
__device__ __forceinline__ void init_acc(f32x16* acc, const float4* ldsBias, int Lb, int hi) {
#pragma unroll
    for (int tg = 0; tg < 2; ++tg) {
        AccLd a;
        const float4* base = &ldsBias[((Lb*2+tg)*2 + hi)*4];
#pragma unroll
        for (int q = 0; q < 4; ++q) a.f4[q] = base[q];
        acc[tg] = a.v;
    }
}

// acc (D layout row=(r&3)+8*(r>>2)+4*hi) -> sin -> hi/lo bf16 B-frags.
// B k-slot map (self-consistent with A staging): frag c=(tg,s), word wi, half p:
//   h = 32*tg + 16*s + 2*(wi&1) + p + 8*(wi>>1) + 4*hi
__device__ __forceinline__ void transitionHL(const f32x16* acc, Frag* Bhi, Frag* Blo) {
#pragma unroll
    for (int tg = 0; tg < 2; ++tg) {
        float sv[16];
#pragma unroll
        for (int r = 0; r < 16; ++r) sv[r] = sin_rev(acc[tg][r]);
#pragma unroll
        for (int s = 0; s < 2; ++s)
#pragma unroll
            for (int wi = 0; wi < 4; ++wi) {
                float a = sv[s*8 + 2*wi], b = sv[s*8 + 2*wi + 1];
                unsigned ph = pk_bf16(a, b);
                Bhi[tg*2+s].u[wi] = ph;
                Blo[tg*2+s].u[wi] = pk_bf16(a - lo_f(ph), b - hi_f(ph));
            }
    }
}

__global__ __launch_bounds__(256, 2)
void siren_kernel(const float* __restrict__ x, const float* __restrict__ W0m,
                  const float* __restrict__ b0, const float* __restrict__ Wm,
                  const float* __restrict__ bm, const float* __restrict__ Wl,
                  const float* __restrict__ bl, float* __restrict__ out)
{
    __shared__ uint4  ldsAhi[3*2*4*64];   // 24KB
    __shared__ uint4  ldsAlo[3*2*4*64];   // 24KB
    __shared__ float4 ldsBias[4*2*2*4];   // 1KB
    __shared__ float  ldsWl[2][32];       // 256B: Wl in acc-slot order per half

    const int tid  = threadIdx.x;
    const int pg   = blockIdx.x;          // point group (0..95)
    const int o    = blockIdx.y;          // subnet (0..15)
    const int lane = tid & 63;
    const int wv   = tid >> 6;
    const int col  = lane & 31;
    const int hi   = lane >> 5;

    // ---- stage mid-layer weight fragments, hi/lo compensated, pre-scaled ----
    for (int idx = tid; idx < 3*2*4*64; idx += 256) {
        int l2  = idx & 63;
        int fi  = idx >> 6;
        int c   = fi & 3;
        int tg  = (fi >> 2) & 1;
        int L   = fi >> 3;
        int hi2 = l2 >> 5;
        int g   = tg*32 + (l2 & 31);
        int th  = c >> 1, s = c & 1;
        const float2* Wrow2 = (const float2*)(Wm + (((size_t)(L*16 + o)*64 + g)*64));
        uint4 whi, wlo;
        unsigned* uh = (unsigned*)&whi;
        unsigned* ul = (unsigned*)&wlo;
#pragma unroll
        for (int wi = 0; wi < 4; ++wi) {
            int h = th*32 + s*16 + 8*(wi>>1) + 2*(wi&1) + 4*hi2;   // even
            float2 wp = Wrow2[h >> 1];
            float a = SCALE*wp.x, b = SCALE*wp.y;
            unsigned ph = pk_bf16(a, b);
            uh[wi] = ph;
            ul[wi] = pk_bf16(a - lo_f(ph), b - hi_f(ph));
        }
        ldsAhi[idx] = whi;
        ldsAlo[idx] = wlo;
    }
    // ---- stage biases (pre-scaled), contiguous per (Lb,tg,hi) ----
    if (tid < 64) {
        int q   = tid & 3;
        int hi2 = (tid >> 2) & 1;
        int tg  = (tid >> 3) & 1;
        int Lb  = tid >> 4;          // 0..2 mid, 3 = first layer
        int h0  = tg*32 + 8*q + 4*hi2;
        const float* bsrc = (Lb < 3) ? (bm + (Lb*16 + o)*64) : (b0 + o*64);
        ldsBias[tid] = make_float4(SCALE*bsrc[h0], SCALE*bsrc[h0+1],
                                   SCALE*bsrc[h0+2], SCALE*bsrc[h0+3]);
    }
    // ---- stage last-layer weights in acc-slot order: ldsWl[hi][tg*16+r] ----
    if (tid >= 64 && tid < 128) {
        int t2  = tid - 64;
        int hi2 = t2 >> 5;
        int idx = t2 & 31;
        int tg  = idx >> 4;
        int r   = idx & 15;
        int s = r >> 3, j = r & 7;
        int h = tg*32 + 16*s + (j & 3) + 8*(j >> 2) + 4*hi2;
        ldsWl[hi2][idx] = Wl[o*64 + h];
    }

    // ---- first-layer A frags, fully compensated ----
    Frag L1A[2];
#pragma unroll
    for (int tg = 0; tg < 2; ++tg) {
        int g = tg*32 + col;
        float2 wp = ((const float2*)W0m)[o*64 + g];
        float s0 = SCALE*wp.x, s1 = SCALE*wp.y;
        unsigned u0 = pk_bf16(s0, s0), u1 = pk_bf16(s1, s1);
        float l0 = s0 - lo_f(u0), l1 = s1 - lo_f(u1);
        L1A[tg].u[0] = hi ? 0u : u0;
        L1A[tg].u[1] = hi ? 0u : u1;
        L1A[tg].u[2] = hi ? 0u : pk_bf16(l0, l0);
        L1A[tg].u[3] = hi ? 0u : pk_bf16(l1, l1);
    }
    const float blv = bl[o] + 0.5f;

    __syncthreads();

    const int tend = ((pg + 1) * NTILES) / NBGROUPS;
    for (int t = (pg * NTILES) / NBGROUPS + wv; t < tend; t += 4) {
        const int pp = t*32 + col;

        // first-layer B: x split hi/lo (exact), duplicated for the W-lo slots
        float2 xv = ((const float2*)x)[pp];
        unsigned ux = pk_bf16(xv.x, xv.y);
        float x0h = lo_f(ux), x1h = hi_f(ux);
        unsigned w0 = pk_bf16(x0h, xv.x - x0h);
        unsigned w1 = pk_bf16(x1h, xv.y - x1h);
        Frag B1;
        B1.u[0] = hi ? 0u : w0;
        B1.u[1] = hi ? 0u : w1;
        B1.u[2] = hi ? 0u : w0;
        B1.u[3] = hi ? 0u : w1;

        f32x16 acc[2];
        init_acc(acc, ldsBias, 3, hi);
        acc[0] = __builtin_amdgcn_mfma_f32_32x32x16_bf16(L1A[0].v, B1.v, acc[0], 0, 0, 0);
        acc[1] = __builtin_amdgcn_mfma_f32_32x32x16_bf16(L1A[1].v, B1.v, acc[1], 0, 0, 0);

        Frag Bhi[4], Blo[4];
        transitionHL(acc, Bhi, Blo);

#pragma unroll
        for (int L = 0; L < 3; ++L) {
            init_acc(acc, ldsBias, L, hi);
#pragma unroll
            for (int c = 0; c < 4; ++c) {
                Frag Ah0, Ah1, Al0, Al1;
                Ah0.q = ldsAhi[((L*2+0)*4+c)*64 + lane];
                Ah1.q = ldsAhi[((L*2+1)*4+c)*64 + lane];
                Al0.q = ldsAlo[((L*2+0)*4+c)*64 + lane];
                Al1.q = ldsAlo[((L*2+1)*4+c)*64 + lane];
                acc[0] = __builtin_amdgcn_mfma_f32_32x32x16_bf16(Ah0.v, Bhi[c].v, acc[0], 0, 0, 0);
                acc[1] = __builtin_amdgcn_mfma_f32_32x32x16_bf16(Ah1.v, Bhi[c].v, acc[1], 0, 0, 0);
                acc[0] = __builtin_amdgcn_mfma_f32_32x32x16_bf16(Ah0.v, Blo[c].v, acc[0], 0, 0, 0);
                acc[1] = __builtin_amdgcn_mfma_f32_32x32x16_bf16(Ah1.v, Blo[c].v, acc[1], 0, 0, 0);
                acc[0] = __builtin_amdgcn_mfma_f32_32x32x16_bf16(Al0.v, Bhi[c].v, acc[0], 0, 0, 0);
                acc[1] = __builtin_amdgcn_mfma_f32_32x32x16_bf16(Al1.v, Bhi[c].v, acc[1], 0, 0, 0);
            }
            if (L < 2) transitionHL(acc, Bhi, Blo);
        }

        // last layer: f32 sin + f32 dot with LDS-broadcast Wl (acc-slot order)
        const float4* wl4 = (const float4*)&ldsWl[hi][0];
        float sum = 0.f;
#pragma unroll
        for (int tg = 0; tg < 2; ++tg)
#pragma unroll
            for (int q = 0; q < 4; ++q) {
                float4 w4 = wl4[tg*4 + q];
                sum = fmaf(sin_rev(acc[tg][q*4+0]), w4.x, sum);
                sum = fmaf(sin_rev(acc[tg][q*4+1]), w4.y, sum);
                sum = fmaf(sin_rev(acc[tg][q*4+2]), w4.z, sum);
                sum = fmaf(sin_rev(acc[tg][q*4+3]), w4.w, sum);
            }
        sum += __shfl_xor(sum, 32);
        if (lane < 32) out[(size_t)pp*16 + o] = sum + blv;
    }
}

extern "C" void kernel_launch(void* const* d_in, const int* in_sizes, int n_in,
                              void* d_out, int out_size, void* d_ws, size_t ws_size,
                              hipStream_t stream) {
    (void)in_sizes; (void)n_in; (void)out_size; (void)d_ws; (void)ws_size;
    siren_kernel<<<dim3(NBGROUPS, 16), dim3(256), 0, stream>>>(
        (const float*)d_in[0], (const float*)d_in[1], (const float*)d_in[2],
        (const float*)d_in[3], (const float*)d_in[4], (const float*)d_in[5],
        (const float*)d_in[6], (float*)d_out);
}

// Round 6
// 344.959 us; speedup vs baseline: 1.2899x; 1.1438x over previous
//
#include <hip/hip_runtime.h>

typedef short bf16x8 __attribute__((ext_vector_type(8)));
typedef float f32x16 __attribute__((ext_vector_type(16)));
typedef float f32x2  __attribute__((ext_vector_type(2)));

#define NBGROUPS 128         // grid = 128 x 16 = 2048 blocks; 64 tiles/block, 8 pair-iters/wave
#define SCALE 4.7746482927568601f   // 30/(2*pi): weights pre-scaled -> args in revolutions

union Frag  { bf16x8 v; unsigned u[4]; uint4 q; };
union AccLd { float4 f4[4]; f32x16 v; };

__device__ __forceinline__ unsigned pk_bf16(float lo, float hi) {
    unsigned r;
    asm("v_cvt_pk_bf16_f32 %0, %1, %2" : "=v"(r) : "v"(lo), "v"(hi));
    return r;
}
__device__ __forceinline__ float lo_f(unsigned w) { return __uint_as_float(w << 16); }
__device__ __forceinline__ float hi_f(unsigned w) { return __uint_as_float(w & 0xffff0000u); }

// packed sin(2*pi*z): v = z - rndne(z) in [-0.5,0.5], deg-9 poly (max err ~6e-6)
__device__ __forceinline__ f32x2 sin2(f32x2 z) {
    f32x2 r  = { rintf(z.x), rintf(z.y) };
    f32x2 v  = z - r;
    f32x2 v2 = v * v;
    f32x2 p  = { 32.765379f, 32.765379f };
    p = __builtin_elementwise_fma(p, v2, (f32x2){-74.468884f, -74.468884f});
    p = __builtin_elementwise_fma(p, v2, (f32x2){ 81.365064f,  81.365064f});
    p = __builtin_elementwise_fma(p, v2, (f32x2){-41.331084f, -41.331084f});
    p = __builtin_elementwise_fma(p, v2, (f32x2){  6.2830526f,  6.2830526f});
    return p * v;
}

// Bias table: [ ((Lb*2+tg)*2 + hi)*4 + q ] float4, contiguous 64B per (Lb,tg,hi).
__device__ __forceinline__ void init_acc(f32x16* acc, const float4* ldsBias, int Lb, int hi) {
#pragma unroll
    for (int tg = 0; tg < 2; ++tg) {
        AccLd a;
        const float4* base = &ldsBias[((Lb*2+tg)*2 + hi)*4];
#pragma unroll
        for (int q = 0; q < 4; ++q) a.f4[q] = base[q];
        acc[tg] = a.v;
    }
}

// acc -> sin -> hi/lo bf16 B-frags. Pair j within tg: slots (2j, 2j+1) -> frag[tg*2+(j>>2)].u[j&3]
__device__ __forceinline__ void transitionHL(const f32x16* acc, Frag* Bhi, Frag* Blo) {
#pragma unroll
    for (int tg = 0; tg < 2; ++tg)
#pragma unroll
        for (int j = 0; j < 8; ++j) {
            f32x2 z = { acc[tg][2*j], acc[tg][2*j+1] };
            f32x2 s = sin2(z);
            unsigned ph = pk_bf16(s.x, s.y);
            f32x2 hf = { lo_f(ph), hi_f(ph) };
            f32x2 d  = s - hf;
            Bhi[tg*2 + (j>>2)].u[j&3] = ph;
            Blo[tg*2 + (j>>2)].u[j&3] = pk_bf16(d.x, d.y);
        }
}
// hi-only (feeds the uncompensated last hidden layer)
__device__ __forceinline__ void transitionH(const f32x16* acc, Frag* Bhi) {
#pragma unroll
    for (int tg = 0; tg < 2; ++tg)
#pragma unroll
        for (int j = 0; j < 8; ++j) {
            f32x2 z = { acc[tg][2*j], acc[tg][2*j+1] };
            f32x2 s = sin2(z);
            Bhi[tg*2 + (j>>2)].u[j&3] = pk_bf16(s.x, s.y);
        }
}

__global__ __launch_bounds__(256, 2)
void siren_kernel(const float* __restrict__ x, const float* __restrict__ W0m,
                  const float* __restrict__ b0, const float* __restrict__ Wm,
                  const float* __restrict__ bm, const float* __restrict__ Wl,
                  const float* __restrict__ bl, float* __restrict__ out)
{
    __shared__ uint4  ldsAhi[3*2*4*64];   // 24KB: hi frags, layers 0..2
    __shared__ uint4  ldsAlo[2*2*4*64];   // 16KB: lo frags, layers 0..1 only
    __shared__ float4 ldsBias[4*2*2*4];   // 1KB
    __shared__ float  ldsWl[2][32];       // 256B: Wl in acc-slot order per half

    const int tid  = threadIdx.x;
    const int pg   = blockIdx.x;          // point group (0..127)
    const int o    = blockIdx.y;          // subnet (0..15)
    const int lane = tid & 63;
    const int wv   = tid >> 6;
    const int col  = lane & 31;
    const int hi   = lane >> 5;

    // ---- stage mid-layer weight fragments, hi/lo compensated, pre-scaled ----
    for (int idx = tid; idx < 3*2*4*64; idx += 256) {
        int l2  = idx & 63;
        int fi  = idx >> 6;
        int c   = fi & 3;
        int tg  = (fi >> 2) & 1;
        int L   = fi >> 3;
        int hi2 = l2 >> 5;
        int g   = tg*32 + (l2 & 31);
        int th  = c >> 1, s = c & 1;
        const float2* Wrow2 = (const float2*)(Wm + (((size_t)(L*16 + o)*64 + g)*64));
        uint4 whi, wlo;
        unsigned* uh = (unsigned*)&whi;
        unsigned* ul = (unsigned*)&wlo;
#pragma unroll
        for (int wi = 0; wi < 4; ++wi) {
            int h = th*32 + s*16 + 8*(wi>>1) + 2*(wi&1) + 4*hi2;   // even
            float2 wp = Wrow2[h >> 1];
            float a = SCALE*wp.x, b = SCALE*wp.y;
            unsigned ph = pk_bf16(a, b);
            uh[wi] = ph;
            ul[wi] = pk_bf16(a - lo_f(ph), b - hi_f(ph));
        }
        ldsAhi[idx] = whi;
        if (idx < 2*2*4*64) ldsAlo[idx] = wlo;   // lo only for L=0,1
    }
    // ---- stage biases (pre-scaled), contiguous per (Lb,tg,hi) ----
    if (tid < 64) {
        int q   = tid & 3;
        int hi2 = (tid >> 2) & 1;
        int tg  = (tid >> 3) & 1;
        int Lb  = tid >> 4;          // 0..2 mid, 3 = first layer
        int h0  = tg*32 + 8*q + 4*hi2;
        const float* bsrc = (Lb < 3) ? (bm + (Lb*16 + o)*64) : (b0 + o*64);
        ldsBias[tid] = make_float4(SCALE*bsrc[h0], SCALE*bsrc[h0+1],
                                   SCALE*bsrc[h0+2], SCALE*bsrc[h0+3]);
    }
    // ---- stage last-layer weights in acc-slot order: ldsWl[hi][tg*16+r] ----
    if (tid >= 64 && tid < 128) {
        int t2  = tid - 64;
        int hi2 = t2 >> 5;
        int idx = t2 & 31;
        int tg  = idx >> 4;
        int r   = idx & 15;
        int s = r >> 3, j = r & 7;
        int h = tg*32 + 16*s + (j & 3) + 8*(j >> 2) + 4*hi2;
        ldsWl[hi2][idx] = Wl[o*64 + h];
    }

    // ---- first-layer A frags, fully compensated ----
    Frag L1A[2];
#pragma unroll
    for (int tg = 0; tg < 2; ++tg) {
        int g = tg*32 + col;
        float2 wp = ((const float2*)W0m)[o*64 + g];
        float s0 = SCALE*wp.x, s1 = SCALE*wp.y;
        unsigned u0 = pk_bf16(s0, s0), u1 = pk_bf16(s1, s1);
        float l0 = s0 - lo_f(u0), l1 = s1 - lo_f(u1);
        L1A[tg].u[0] = hi ? 0u : u0;
        L1A[tg].u[1] = hi ? 0u : u1;
        L1A[tg].u[2] = hi ? 0u : pk_bf16(l0, l0);
        L1A[tg].u[3] = hi ? 0u : pk_bf16(l1, l1);
    }
    const float blv = bl[o] + 0.5f;

    __syncthreads();

    const int tbase = pg*64 + wv;
#pragma unroll 1
    for (int k = 0; k < 8; ++k) {
        const int ta  = tbase + 8*k;
        const int ppa = ta*32 + col;
        const int ppb = ppa + 128;       // tile tb = ta + 4

        // ---- first layer, both tiles ----
        float2 xa = ((const float2*)x)[ppa];
        float2 xb = ((const float2*)x)[ppb];
        Frag B1a, B1b;
        {
            unsigned ux = pk_bf16(xa.x, xa.y);
            float x0h = lo_f(ux), x1h = hi_f(ux);
            unsigned w0 = pk_bf16(x0h, xa.x - x0h);
            unsigned w1 = pk_bf16(x1h, xa.y - x1h);
            B1a.u[0] = hi ? 0u : w0;  B1a.u[1] = hi ? 0u : w1;
            B1a.u[2] = hi ? 0u : w0;  B1a.u[3] = hi ? 0u : w1;
            ux = pk_bf16(xb.x, xb.y);
            x0h = lo_f(ux); x1h = hi_f(ux);
            w0 = pk_bf16(x0h, xb.x - x0h);
            w1 = pk_bf16(x1h, xb.y - x1h);
            B1b.u[0] = hi ? 0u : w0;  B1b.u[1] = hi ? 0u : w1;
            B1b.u[2] = hi ? 0u : w0;  B1b.u[3] = hi ? 0u : w1;
        }

        f32x16 accA[2], accB[2];
        init_acc(accA, ldsBias, 3, hi);
        init_acc(accB, ldsBias, 3, hi);
        accA[0] = __builtin_amdgcn_mfma_f32_32x32x16_bf16(L1A[0].v, B1a.v, accA[0], 0, 0, 0);
        accA[1] = __builtin_amdgcn_mfma_f32_32x32x16_bf16(L1A[1].v, B1a.v, accA[1], 0, 0, 0);
        accB[0] = __builtin_amdgcn_mfma_f32_32x32x16_bf16(L1A[0].v, B1b.v, accB[0], 0, 0, 0);
        accB[1] = __builtin_amdgcn_mfma_f32_32x32x16_bf16(L1A[1].v, B1b.v, accB[1], 0, 0, 0);

        Frag BhiA[4], BloA[4], BhiB[4], BloB[4];
        transitionHL(accA, BhiA, BloA);
        transitionHL(accB, BhiB, BloB);

        // ---- mid layers 0,1: full 3-term compensation ----
#pragma unroll
        for (int L = 0; L < 2; ++L) {
            init_acc(accA, ldsBias, L, hi);
            init_acc(accB, ldsBias, L, hi);
#pragma unroll
            for (int c = 0; c < 4; ++c) {
                Frag Ah0, Ah1, Al0, Al1;
                Ah0.q = ldsAhi[((L*2+0)*4+c)*64 + lane];
                Ah1.q = ldsAhi[((L*2+1)*4+c)*64 + lane];
                Al0.q = ldsAlo[((L*2+0)*4+c)*64 + lane];
                Al1.q = ldsAlo[((L*2+1)*4+c)*64 + lane];
                accA[0] = __builtin_amdgcn_mfma_f32_32x32x16_bf16(Ah0.v, BhiA[c].v, accA[0], 0, 0, 0);
                accA[1] = __builtin_amdgcn_mfma_f32_32x32x16_bf16(Ah1.v, BhiA[c].v, accA[1], 0, 0, 0);
                accB[0] = __builtin_amdgcn_mfma_f32_32x32x16_bf16(Ah0.v, BhiB[c].v, accB[0], 0, 0, 0);
                accB[1] = __builtin_amdgcn_mfma_f32_32x32x16_bf16(Ah1.v, BhiB[c].v, accB[1], 0, 0, 0);
                accA[0] = __builtin_amdgcn_mfma_f32_32x32x16_bf16(Ah0.v, BloA[c].v, accA[0], 0, 0, 0);
                accA[1] = __builtin_amdgcn_mfma_f32_32x32x16_bf16(Ah1.v, BloA[c].v, accA[1], 0, 0, 0);
                accB[0] = __builtin_amdgcn_mfma_f32_32x32x16_bf16(Ah0.v, BloB[c].v, accB[0], 0, 0, 0);
                accB[1] = __builtin_amdgcn_mfma_f32_32x32x16_bf16(Ah1.v, BloB[c].v, accB[1], 0, 0, 0);
                accA[0] = __builtin_amdgcn_mfma_f32_32x32x16_bf16(Al0.v, BhiA[c].v, accA[0], 0, 0, 0);
                accA[1] = __builtin_amdgcn_mfma_f32_32x32x16_bf16(Al1.v, BhiA[c].v, accA[1], 0, 0, 0);
                accB[0] = __builtin_amdgcn_mfma_f32_32x32x16_bf16(Al0.v, BhiB[c].v, accB[0], 0, 0, 0);
                accB[1] = __builtin_amdgcn_mfma_f32_32x32x16_bf16(Al1.v, BhiB[c].v, accB[1], 0, 0, 0);
            }
            if (L == 0) {
                transitionHL(accA, BhiA, BloA);
                transitionHL(accB, BhiB, BloB);
            } else {
                transitionH(accA, BhiA);
                transitionH(accB, BhiB);
            }
        }

        // ---- mid layer 2: hi-only (errors pass only through final linear dot) ----
        init_acc(accA, ldsBias, 2, hi);
        init_acc(accB, ldsBias, 2, hi);
#pragma unroll
        for (int c = 0; c < 4; ++c) {
            Frag Ah0, Ah1;
            Ah0.q = ldsAhi[((2*2+0)*4+c)*64 + lane];
            Ah1.q = ldsAhi[((2*2+1)*4+c)*64 + lane];
            accA[0] = __builtin_amdgcn_mfma_f32_32x32x16_bf16(Ah0.v, BhiA[c].v, accA[0], 0, 0, 0);
            accA[1] = __builtin_amdgcn_mfma_f32_32x32x16_bf16(Ah1.v, BhiA[c].v, accA[1], 0, 0, 0);
            accB[0] = __builtin_amdgcn_mfma_f32_32x32x16_bf16(Ah0.v, BhiB[c].v, accB[0], 0, 0, 0);
            accB[1] = __builtin_amdgcn_mfma_f32_32x32x16_bf16(Ah1.v, BhiB[c].v, accB[1], 0, 0, 0);
        }

        // ---- last layer: packed f32 sin + dot with LDS-broadcast Wl ----
        const f32x2* wl2 = (const f32x2*)&ldsWl[hi][0];
        f32x2 sa = {0.f, 0.f}, sb = {0.f, 0.f};
#pragma unroll
        for (int tg = 0; tg < 2; ++tg)
#pragma unroll
            for (int j = 0; j < 8; ++j) {
                f32x2 w = wl2[tg*8 + j];
                f32x2 za = { accA[tg][2*j], accA[tg][2*j+1] };
                f32x2 zb = { accB[tg][2*j], accB[tg][2*j+1] };
                sa = __builtin_elementwise_fma(sin2(za), w, sa);
                sb = __builtin_elementwise_fma(sin2(zb), w, sb);
            }
        float suma = sa.x + sa.y;
        float sumb = sb.x + sb.y;
        suma += __shfl_xor(suma, 32);
        sumb += __shfl_xor(sumb, 32);
        if (lane < 32) {
            out[(size_t)ppa*16 + o] = suma + blv;
            out[(size_t)ppb*16 + o] = sumb + blv;
        }
    }
}

extern "C" void kernel_launch(void* const* d_in, const int* in_sizes, int n_in,
                              void* d_out, int out_size, void* d_ws, size_t ws_size,
                              hipStream_t stream) {
    (void)in_sizes; (void)n_in; (void)out_size; (void)d_ws; (void)ws_size;
    siren_kernel<<<dim3(NBGROUPS, 16), dim3(256), 0, stream>>>(
        (const float*)d_in[0], (const float*)d_in[1], (const float*)d_in[2],
        (const float*)d_in[3], (const float*)d_in[4], (const float*)d_in[5],
        (const float*)d_in[6], (float*)d_out);
}